// Round 10
// baseline (316.944 us; speedup 1.0000x reference)
//
#include <hip/hip_runtime.h>

typedef __attribute__((ext_vector_type(8))) short bf16x8_t;
typedef __attribute__((ext_vector_type(4))) float f32x4_t;

#define B_   128
#define L_   50
#define D_   64
#define N_   6400     // B_*L_
#define KC   1024
#define STRD 72       // LDS row stride in bf16 units (144B): b128 frag reads 2-way max

// float -> bf16 bits, round-to-nearest-even
static __device__ __forceinline__ unsigned short f2b(float x) {
    union { float f; unsigned int u; } c; c.f = x;
    return (unsigned short)((c.u + 0x7FFFu + ((c.u >> 16) & 1u)) >> 16);
}

// ---------------------------------------------------------------------------
// Blocks 0..399:   embedding+mask+QKV -> bf16 q, k, vT.
// Blocks 400..403: codebook norms (fp32) + bf16 codebook copy.
// Block  404:      out[b][d] = b_enc[d]; zero the per-q-tile completion
//                  counters (re-done every launch: d_out/d_ws re-poisoned).
// ---------------------------------------------------------------------------
__global__ __launch_bounds__(256) void k_qkv(
    const int* __restrict__ ids, const int* __restrict__ masks,
    const float* __restrict__ emb,
    const float* __restrict__ Wq, const float* __restrict__ bq,
    const float* __restrict__ Wk, const float* __restrict__ bk,
    const float* __restrict__ Wv, const float* __restrict__ bv,
    const float* __restrict__ cbf, const float* __restrict__ benc,
    unsigned short* __restrict__ q, unsigned short* __restrict__ k,
    unsigned short* __restrict__ vt,
    float* __restrict__ cn, unsigned short* __restrict__ cbb,
    float* __restrict__ out, unsigned int* __restrict__ cnt)
{
    const int tid = threadIdx.x;
    if (blockIdx.x >= 404) {      // ---- init out = benc; zero tile counters
        for (int i = tid; i < B_ * 64; i += 256) out[i] = benc[i & 63];
        if (tid < 200) cnt[tid] = 0u;
        return;
    }
    if (blockIdx.x >= 400) {      // ---- cnorm: codes c = (bid-400)*256+tid
        const int c = (blockIdx.x - 400) * 256 + tid;
        float s = 0.f;
        #pragma unroll
        for (int d4 = 0; d4 < 16; ++d4) {
            float4 x = ((const float4*)cbf)[c * 16 + d4];
            s = fmaf(x.x, x.x, s); s = fmaf(x.y, x.y, s);
            s = fmaf(x.z, x.z, s); s = fmaf(x.w, x.w, s);
            ushort4 u;
            u.x = f2b(x.x); u.y = f2b(x.y); u.z = f2b(x.z); u.w = f2b(x.w);
            *(ushort4*)&cbb[c * 64 + d4 * 4] = u;
        }
        cn[c] = s;
        return;
    }

    __shared__ float Ws[3 * 64 * 64];
    __shared__ float hs[16][64];
    const int n0  = blockIdx.x * 16;

    {   // stage Wq|Wk|Wv (3*1024 float4)
        const float4* wq4 = (const float4*)Wq;
        const float4* wk4 = (const float4*)Wk;
        const float4* wv4 = (const float4*)Wv;
        float4* ws4 = (float4*)Ws;
        #pragma unroll
        for (int i = 0; i < 4; ++i) ws4[i*256 + tid]        = wq4[i*256 + tid];
        #pragma unroll
        for (int i = 0; i < 4; ++i) ws4[1024 + i*256 + tid] = wk4[i*256 + tid];
        #pragma unroll
        for (int i = 0; i < 4; ++i) ws4[2048 + i*256 + tid] = wv4[i*256 + tid];
    }
    {   // stage h = emb[id]*mask
        const int t  = tid >> 4, c4 = tid & 15;
        const int n  = n0 + t;
        const int id = ids[n];
        const float m = (masks[n] >= 1) ? 1.0f : 0.0f;
        float4 e = ((const float4*)emb)[id * 16 + c4];
        ((float4*)&hs[t][0])[c4] = make_float4(e.x*m, e.y*m, e.z*m, e.w*m);
    }
    __syncthreads();

    const int j  = tid & 63;
    const int tg = tid >> 6;
    const float bqj = bq[j], bkj = bk[j], bvj = bv[j];
    #pragma unroll
    for (int p = 0; p < 4; ++p) {
        const int t = p * 4 + tg;
        float aq = bqj, ak = bkj, av = bvj;
        #pragma unroll 8
        for (int d = 0; d < 64; ++d) {
            const float hd = hs[t][d];
            aq = fmaf(hd, Ws[d*64 + j],        aq);
            ak = fmaf(hd, Ws[4096 + d*64 + j], ak);
            av = fmaf(hd, Ws[8192 + d*64 + j], av);
        }
        const int n = n0 + t;
        q[n*64 + j]   = f2b(aq);
        k[n*64 + j]   = f2b(ak);
        vt[j*N_ + n]  = f2b(av);     // transposed store for PV B-operand
    }
}

// ---------------------------------------------------------------------------
// Flash attention + fused VQ/encoder tail, 2-node structure.
// Grid 800 = 200 q-tiles (TQ=32) x 4 KV-quarters (25 steps of 64).
// launch_bounds(256,4): LDS 36352B -> 4 blk/CU -> all 800 co-resident.
// Main body identical to round-9 k_attn (HW-proven, absmax 4.9e-4).
// Tail: last-block-done per q-tile (threadfence + syncthreads + atomicAdd,
// Guideline-16-sanctioned; no dispatch-order assumption, no spin-wait):
// the 4th finisher re-fences then runs the round-9 k_vq body in waves 0/1
// (one 16-token half each; body is wave-local shfl-only).
// ---------------------------------------------------------------------------
__global__ __launch_bounds__(256, 4) void k_attn(
    const unsigned short* __restrict__ qg, const unsigned short* __restrict__ kg,
    const unsigned short* __restrict__ vtg,
    float* __restrict__ opart, float* __restrict__ lpart,
    const unsigned short* __restrict__ cbb, const float* __restrict__ cn,
    const float* __restrict__ cbf, const int* __restrict__ masks,
    const float* __restrict__ Wenc, float* __restrict__ out,
    unsigned int* __restrict__ cnt)
{
    __shared__ unsigned short Qs[32 * STRD];
    __shared__ unsigned short Ks[64 * STRD];
    __shared__ unsigned short Vts[64 * STRD];
    __shared__ unsigned short Ps[32 * STRD];
    __shared__ float Of[32 * 66];
    __shared__ float lred[2][32];
    __shared__ int lastFlag;

    const int tid  = threadIdx.x;
    const int qt   = blockIdx.x >> 2;
    const int sp   = blockIdx.x & 3;
    const int q0   = qt * 32;
    const int kvb  = sp * 1600;
    const int lane = tid & 63;
    const int w    = tid >> 6;
    const int m    = w & 1;          // q 16-row subtile
    const int s    = w >> 1;         // kv 32-col half of each step
    const int lr   = lane & 15;      // frag row/col id
    const int lg   = lane >> 4;      // frag k-group

    {   // stage Q tile: 32 rows x 64 bf16
        const int row = tid >> 3, ch = tid & 7;
        uint4 t = *(const uint4*)&qg[(q0 + row) * 64 + ch * 8];
        *(uint4*)&Qs[row * STRD + ch * 8] = t;
    }
    __syncthreads();
    const bf16x8_t qa0 = *(const bf16x8_t*)&Qs[(m*16 + lr) * STRD +  0 + lg*8];
    const bf16x8_t qa1 = *(const bf16x8_t*)&Qs[(m*16 + lr) * STRD + 32 + lg*8];

    f32x4_t o0 = {0.f,0.f,0.f,0.f}, o1 = {0.f,0.f,0.f,0.f};
    f32x4_t o2 = {0.f,0.f,0.f,0.f}, o3 = {0.f,0.f,0.f,0.f};
    float ls0 = 0.f, ls1 = 0.f, ls2 = 0.f, ls3 = 0.f;
    const float scale = 0.125f;   // 1/sqrt(64)

    for (int st = 0; st < 25; ++st) {
        __syncthreads();               // all waves done reading Ks/Vts
        const int j0 = kvb + st * 64;
        {   // stage K[64][64] and Vt[64][64]: 4 x 16B per thread
            const int row = tid >> 3, ch = tid & 7;     // row 0..31
            uint4 a = *(const uint4*)&kg [(j0 + row)      * 64 + ch*8];
            uint4 b = *(const uint4*)&kg [(j0 + row + 32) * 64 + ch*8];
            uint4 c = *(const uint4*)&vtg[ row       * N_ + j0 + ch*8];
            uint4 d = *(const uint4*)&vtg[(row + 32) * N_ + j0 + ch*8];
            *(uint4*)&Ks [ row      * STRD + ch*8] = a;
            *(uint4*)&Ks [(row+32)  * STRD + ch*8] = b;
            *(uint4*)&Vts[ row      * STRD + ch*8] = c;
            *(uint4*)&Vts[(row+32)  * STRD + ch*8] = d;
        }
        __syncthreads();

        // ---- QK^T + exp + P write (kv cols s*32 + t*16 + lr)
        #pragma unroll
        for (int t = 0; t < 2; ++t) {
            const int kcol = s*32 + t*16 + lr;
            bf16x8_t kb0 = *(const bf16x8_t*)&Ks[kcol * STRD +  0 + lg*8];
            bf16x8_t kb1 = *(const bf16x8_t*)&Ks[kcol * STRD + 32 + lg*8];
            f32x4_t acc = {0.f,0.f,0.f,0.f};
            acc = __builtin_amdgcn_mfma_f32_16x16x32_bf16(qa0, kb0, acc, 0, 0, 0);
            acc = __builtin_amdgcn_mfma_f32_16x16x32_bf16(qa1, kb1, acc, 0, 0, 0);
            const float p0 = __expf(acc[0] * scale);
            const float p1 = __expf(acc[1] * scale);
            const float p2 = __expf(acc[2] * scale);
            const float p3 = __expf(acc[3] * scale);
            ls0 += p0; ls1 += p1; ls2 += p2; ls3 += p3;
            const int rb = (m*16 + lg*4) * STRD + kcol;
            Ps[rb           ] = f2b(p0);
            Ps[rb +   STRD  ] = f2b(p1);
            Ps[rb + 2*STRD  ] = f2b(p2);
            Ps[rb + 3*STRD  ] = f2b(p3);
        }
        // no barrier: wave-private P region; in-wave lgkmcnt orders write->read

        // ---- PV over this wave's kv half
        const bf16x8_t pa = *(const bf16x8_t*)&Ps[(m*16 + lr) * STRD + s*32 + lg*8];
        {
            bf16x8_t vb;
            vb = *(const bf16x8_t*)&Vts[( 0 + lr) * STRD + s*32 + lg*8];
            o0 = __builtin_amdgcn_mfma_f32_16x16x32_bf16(pa, vb, o0, 0, 0, 0);
            vb = *(const bf16x8_t*)&Vts[(16 + lr) * STRD + s*32 + lg*8];
            o1 = __builtin_amdgcn_mfma_f32_16x16x32_bf16(pa, vb, o1, 0, 0, 0);
            vb = *(const bf16x8_t*)&Vts[(32 + lr) * STRD + s*32 + lg*8];
            o2 = __builtin_amdgcn_mfma_f32_16x16x32_bf16(pa, vb, o2, 0, 0, 0);
            vb = *(const bf16x8_t*)&Vts[(48 + lr) * STRD + s*32 + lg*8];
            o3 = __builtin_amdgcn_mfma_f32_16x16x32_bf16(pa, vb, o3, 0, 0, 0);
        }
    }

    // ---- row-sum reduce over the 16 kv-lanes, stash per (s, row)
    #pragma unroll
    for (int off = 1; off <= 8; off <<= 1) {
        ls0 += __shfl_xor(ls0, off);
        ls1 += __shfl_xor(ls1, off);
        ls2 += __shfl_xor(ls2, off);
        ls3 += __shfl_xor(ls3, off);
    }
    if (lr == 0) {
        const int rb = m*16 + lg*4;
        lred[s][rb    ] = ls0;
        lred[s][rb + 1] = ls1;
        lred[s][rb + 2] = ls2;
        lred[s][rb + 3] = ls3;
    }

    // ---- merge the two kv-half waves' O in LDS, plain-store to slice sp
    if (s == 0) {
        #pragma unroll
        for (int r = 0; r < 4; ++r) {
            const int row = m*16 + lg*4 + r;
            Of[row*66 +  0 + lr] = o0[r];
            Of[row*66 + 16 + lr] = o1[r];
            Of[row*66 + 32 + lr] = o2[r];
            Of[row*66 + 48 + lr] = o3[r];
        }
    }
    __syncthreads();
    if (s == 1) {
        float* op = opart + ((size_t)sp * N_ + q0) * 64;
        #pragma unroll
        for (int r = 0; r < 4; ++r) {
            const int row = m*16 + lg*4 + r;
            op[row*64 +  0 + lr] = Of[row*66 +  0 + lr] + o0[r];
            op[row*64 + 16 + lr] = Of[row*66 + 16 + lr] + o1[r];
            op[row*64 + 32 + lr] = Of[row*66 + 32 + lr] + o2[r];
            op[row*64 + 48 + lr] = Of[row*66 + 48 + lr] + o3[r];
        }
    }
    if (tid < 32) lpart[sp*N_ + q0 + tid] = lred[0][tid] + lred[1][tid];

    // ==== last-block-done gate (Guideline 16: fence + device atomic) ====
    __threadfence();                   // each thread's stores -> device scope
    __syncthreads();                   // all threads' fences done
    if (tid == 0) lastFlag = (atomicAdd(&cnt[qt], 1u) == 3u);
    __syncthreads();
    if (!lastFlag) return;
    __threadfence();                   // acquire: see other splits' stores

    // ================= fused VQ + encoder tail (round-9 k_vq body) ========
    if (tid >= 128) return;           // waves 0,1: one 16-token half each
    {
        const int n0  = q0 + w * 16;
        const int row = n0 + lr;

        const float l = lpart[row] + lpart[N_ + row]
                      + lpart[2*N_ + row] + lpart[3*N_ + row];
        const float inv = 1.0f / l;      // lanes 0..15: inv for tokens 0..15

        float fr[16];
        #pragma unroll
        for (int h = 0; h < 2; ++h) {
            const int base = row*64 + h*32 + lg*8;
            float4 s0 = *(const float4*)&opart[base];
            float4 s1 = *(const float4*)&opart[(size_t)N_*64   + base];
            float4 s2 = *(const float4*)&opart[(size_t)N_*64*2 + base];
            float4 s3 = *(const float4*)&opart[(size_t)N_*64*3 + base];
            float4 t0 = *(const float4*)&opart[base + 4];
            float4 t1 = *(const float4*)&opart[(size_t)N_*64   + base + 4];
            float4 t2 = *(const float4*)&opart[(size_t)N_*64*2 + base + 4];
            float4 t3 = *(const float4*)&opart[(size_t)N_*64*3 + base + 4];
            fr[h*8+0] = ((s0.x+s1.x)+s2.x)+s3.x;  fr[h*8+1] = ((s0.y+s1.y)+s2.y)+s3.y;
            fr[h*8+2] = ((s0.z+s1.z)+s2.z)+s3.z;  fr[h*8+3] = ((s0.w+s1.w)+s2.w)+s3.w;
            fr[h*8+4] = ((t0.x+t1.x)+t2.x)+t3.x;  fr[h*8+5] = ((t0.y+t1.y)+t2.y)+t3.y;
            fr[h*8+6] = ((t0.z+t1.z)+t2.z)+t3.z;  fr[h*8+7] = ((t0.w+t1.w)+t2.w)+t3.w;
        }
        bf16x8_t fa0, fa1;
        #pragma unroll
        for (int i = 0; i < 8; ++i) {
            fa0[i] = (short)f2b(fr[i]     * inv);
            fa1[i] = (short)f2b(fr[8 + i] * inv);
        }

        float best0 = 3.0e38f, best1 = 3.0e38f, best2 = 3.0e38f, best3 = 3.0e38f;
        int   bi0 = 0, bi1 = 0, bi2 = 0, bi3 = 0;

        #pragma unroll 4
        for (int st = 0; st < 64; ++st) {
            const int crow = st * 16 + lr;
            bf16x8_t cb0 = *(const bf16x8_t*)&cbb[crow * 64 +  0 + lg*8];
            bf16x8_t cb1 = *(const bf16x8_t*)&cbb[crow * 64 + 32 + lg*8];
            const float cnv = cn[crow];
            f32x4_t acc = {0.f,0.f,0.f,0.f};
            acc = __builtin_amdgcn_mfma_f32_16x16x32_bf16(fa0, cb0, acc, 0, 0, 0);
            acc = __builtin_amdgcn_mfma_f32_16x16x32_bf16(fa1, cb1, acc, 0, 0, 0);
            const float d0 = fmaf(-2.f, acc[0], cnv);
            const float d1 = fmaf(-2.f, acc[1], cnv);
            const float d2 = fmaf(-2.f, acc[2], cnv);
            const float d3 = fmaf(-2.f, acc[3], cnv);
            if (d0 < best0) { best0 = d0; bi0 = crow; }
            if (d1 < best1) { best1 = d1; bi1 = crow; }
            if (d2 < best2) { best2 = d2; bi2 = crow; }
            if (d3 < best3) { best3 = d3; bi3 = crow; }
        }

        #pragma unroll
        for (int off = 1; off <= 8; off <<= 1) {
            float ov; int oi;
            ov = __shfl_xor(best0, off); oi = __shfl_xor(bi0, off);
            if (ov < best0 || (ov == best0 && oi < bi0)) { best0 = ov; bi0 = oi; }
            ov = __shfl_xor(best1, off); oi = __shfl_xor(bi1, off);
            if (ov < best1 || (ov == best1 && oi < bi1)) { best1 = ov; bi1 = oi; }
            ov = __shfl_xor(best2, off); oi = __shfl_xor(bi2, off);
            if (ov < best2 || (ov == best2 && oi < bi2)) { best2 = ov; bi2 = oi; }
            ov = __shfl_xor(best3, off); oi = __shfl_xor(bi3, off);
            if (ov < best3 || (ov == best3 && oi < bi3)) { best3 = ov; bi3 = oi; }
        }
        // token t (= lg*4 + r) winner: reg bi_{t&3} of lanes with lg == t>>2

        // ---- per-batch partial sums: lane = dim d
        const int d  = lane;
        const int b0 = n0 / 50;
        const int r0 = n0 - b0 * 50;
        float vq0 = 0.f, hi0 = 0.f, vq1 = 0.f, hi1 = 0.f;
        #pragma unroll
        for (int t = 0; t < 16; ++t) {
            int ci;
            switch (t & 3) {
                case 0:  ci = __shfl(bi0, (t >> 2) * 16); break;
                case 1:  ci = __shfl(bi1, (t >> 2) * 16); break;
                case 2:  ci = __shfl(bi2, (t >> 2) * 16); break;
                default: ci = __shfl(bi3, (t >> 2) * 16); break;
            }
            const float invt = __shfl(inv, t);
            const int   nb   = (n0 + t) * 64 + d;
            const float hv = (((opart[nb] + opart[(size_t)N_*64 + nb])
                             + opart[(size_t)N_*64*2 + nb])
                             + opart[(size_t)N_*64*3 + nb]) * invt;
            const float vv = cbf[ci * 64 + d];
            if (r0 + t < 50) { vq0 += vv; hi0 += hv; }
            else             { vq1 += vv; hi1 += hv; }
        }

        // ---- dn for b0 (and b0+1 if spanning), wave-reduced from masks
        int mv0 = (lane < 50) ? ((masks[b0*50 + lane] >= 1) ? 1 : 0) : 0;
        #pragma unroll
        for (int off = 1; off <= 32; off <<= 1) mv0 += __shfl_xor(mv0, off);
        const float dn0 = (float)mv0;

        {   // ---- fused encoder contribution for b0
            const float iv = 1.0f / dn0, ih = 1.0f / (dn0 + 1e-9f);
            float c0 = 0.f;
            #pragma unroll 8
            for (int dp = 0; dp < 64; ++dp) {
                c0 = fmaf(__shfl(vq0, dp) * iv, Wenc[dp*64 + d], c0);
                c0 = fmaf(__shfl(hi0, dp) * ih, Wenc[(64 + dp)*64 + d], c0);
            }
            atomicAdd(&out[b0*64 + d], c0);
        }
        if (r0 + 15 >= 50) {
            const int b1 = b0 + 1;
            int mv1 = (lane < 50) ? ((masks[b1*50 + lane] >= 1) ? 1 : 0) : 0;
            #pragma unroll
            for (int off = 1; off <= 32; off <<= 1) mv1 += __shfl_xor(mv1, off);
            const float dn1 = (float)mv1;
            const float iv = 1.0f / dn1, ih = 1.0f / (dn1 + 1e-9f);
            float c1 = 0.f;
            #pragma unroll 8
            for (int dp = 0; dp < 64; ++dp) {
                c1 = fmaf(__shfl(vq1, dp) * iv, Wenc[dp*64 + d], c1);
                c1 = fmaf(__shfl(hi1, dp) * ih, Wenc[(64 + dp)*64 + d], c1);
            }
            atomicAdd(&out[b1*64 + d], c1);
        }
    }
}

// ---------------------------------------------------------------------------
extern "C" void kernel_launch(void* const* d_in, const int* in_sizes, int n_in,
                              void* d_out, int out_size, void* d_ws, size_t ws_size,
                              hipStream_t stream)
{
    const int*   ids   = (const int*)  d_in[0];
    const int*   masks = (const int*)  d_in[1];
    const float* emb   = (const float*)d_in[2];
    const float* cb    = (const float*)d_in[3];
    const float* Wq    = (const float*)d_in[4];
    const float* bq    = (const float*)d_in[5];
    const float* Wk    = (const float*)d_in[6];
    const float* bk    = (const float*)d_in[7];
    const float* Wv    = (const float*)d_in[8];
    const float* bv    = (const float*)d_in[9];
    const float* Wenc  = (const float*)d_in[10];
    const float* benc  = (const float*)d_in[11];
    float* out = (float*)d_out;

    // workspace layout (bytes), total 9249792 (ws_size = 256 MiB per
    // poison-fill WRITE_SIZE evidence)
    char* w = (char*)d_ws;
    unsigned short* qb    = (unsigned short*)(w);             //  819200
    unsigned short* kb    = (unsigned short*)(w +  819200);   //  819200
    unsigned short* vtb   = (unsigned short*)(w + 1638400);   //  819200
    float*          opart = (float*)        (w + 2457600);    // 6553600 (4 slices)
    float*          lpart = (float*)        (w + 9011200);    //  102400 (4 slices)
    float*          cn    = (float*)        (w + 9113600);    //    4096
    unsigned short* cbb   = (unsigned short*)(w + 9117696);   //  131072
    unsigned int*   cnt   = (unsigned int*) (w + 9248768);    //    1024

    hipLaunchKernelGGL(k_qkv,  dim3(405), dim3(256), 0, stream,
                       ids, masks, emb, Wq, bq, Wk, bk, Wv, bv, cb, benc,
                       qb, kb, vtb, cn, cbb, out, cnt);
    hipLaunchKernelGGL(k_attn, dim3(800), dim3(256), 0, stream,
                       qb, kb, vtb, opart, lpart, cbb, cn, cb, masks,
                       Wenc, out, cnt);
}

// Round 11
// 156.645 us; speedup vs baseline: 2.0233x; 2.0233x over previous
//
#include <hip/hip_runtime.h>

typedef __attribute__((ext_vector_type(8))) short bf16x8_t;
typedef __attribute__((ext_vector_type(4))) float f32x4_t;

#define B_   128
#define L_   50
#define D_   64
#define N_   6400     // B_*L_
#define KC   1024
#define STRD 72       // LDS row stride in bf16 units (144B): b128 frag reads 2-way max

// float -> bf16 bits, round-to-nearest-even
static __device__ __forceinline__ unsigned short f2b(float x) {
    union { float f; unsigned int u; } c; c.f = x;
    return (unsigned short)((c.u + 0x7FFFu + ((c.u >> 16) & 1u)) >> 16);
}

// ---------------------------------------------------------------------------
// Blocks 0..399:   embedding+mask+QKV -> bf16 q, k, vT.
// Blocks 400..403: codebook norms (fp32) + bf16 codebook copy.
// Block  404:      out[b][d] = b_enc[d]  (k_vq atomically adds onto this).
// Compute phase: thread (t, j4) = (token, 4-col group), float4 W reads --
// 256 LDS instrs/thread vs 1024 scalar (r10 post-mortem: k_qkv LDS-bound).
// Same per-output fmaf chain over d => bit-identical to rounds 4-9.
// ---------------------------------------------------------------------------
__global__ __launch_bounds__(256) void k_qkv(
    const int* __restrict__ ids, const int* __restrict__ masks,
    const float* __restrict__ emb,
    const float* __restrict__ Wq, const float* __restrict__ bq,
    const float* __restrict__ Wk, const float* __restrict__ bk,
    const float* __restrict__ Wv, const float* __restrict__ bv,
    const float* __restrict__ cbf, const float* __restrict__ benc,
    unsigned short* __restrict__ q, unsigned short* __restrict__ k,
    unsigned short* __restrict__ vt,
    float* __restrict__ cn, unsigned short* __restrict__ cbb,
    float* __restrict__ out)
{
    const int tid = threadIdx.x;
    if (blockIdx.x >= 404) {      // ---- init out = benc (128x64)
        for (int i = tid; i < B_ * 64; i += 256) out[i] = benc[i & 63];
        return;
    }
    if (blockIdx.x >= 400) {      // ---- cnorm: codes c = (bid-400)*256+tid
        const int c = (blockIdx.x - 400) * 256 + tid;
        float s = 0.f;
        #pragma unroll
        for (int d4 = 0; d4 < 16; ++d4) {
            float4 x = ((const float4*)cbf)[c * 16 + d4];
            s = fmaf(x.x, x.x, s); s = fmaf(x.y, x.y, s);
            s = fmaf(x.z, x.z, s); s = fmaf(x.w, x.w, s);
            ushort4 u;
            u.x = f2b(x.x); u.y = f2b(x.y); u.z = f2b(x.z); u.w = f2b(x.w);
            *(ushort4*)&cbb[c * 64 + d4 * 4] = u;
        }
        cn[c] = s;
        return;
    }

    __shared__ float Ws[3 * 64 * 64];
    __shared__ float hs[16][64];
    const int n0  = blockIdx.x * 16;

    {   // stage Wq|Wk|Wv (3*1024 float4)
        const float4* wq4 = (const float4*)Wq;
        const float4* wk4 = (const float4*)Wk;
        const float4* wv4 = (const float4*)Wv;
        float4* ws4 = (float4*)Ws;
        #pragma unroll
        for (int i = 0; i < 4; ++i) ws4[i*256 + tid]        = wq4[i*256 + tid];
        #pragma unroll
        for (int i = 0; i < 4; ++i) ws4[1024 + i*256 + tid] = wk4[i*256 + tid];
        #pragma unroll
        for (int i = 0; i < 4; ++i) ws4[2048 + i*256 + tid] = wv4[i*256 + tid];
    }
    {   // stage h = emb[id]*mask
        const int t  = tid >> 4, c4 = tid & 15;
        const int n  = n0 + t;
        const int id = ids[n];
        const float m = (masks[n] >= 1) ? 1.0f : 0.0f;
        float4 e = ((const float4*)emb)[id * 16 + c4];
        ((float4*)&hs[t][0])[c4] = make_float4(e.x*m, e.y*m, e.z*m, e.w*m);
    }
    __syncthreads();

    const int t  = tid >> 4;          // token 0..15
    const int j4 = tid & 15;          // 4-col group: cols 4*j4..4*j4+3
    float4 aq = ((const float4*)bq)[j4];
    float4 ak = ((const float4*)bk)[j4];
    float4 av = ((const float4*)bv)[j4];
    #pragma unroll 8
    for (int d = 0; d < 64; ++d) {
        const float hd = hs[t][d];
        const float4 wq = *(const float4*)&Ws[d*64 + 4*j4];
        const float4 wk = *(const float4*)&Ws[4096 + d*64 + 4*j4];
        const float4 wv = *(const float4*)&Ws[8192 + d*64 + 4*j4];
        aq.x = fmaf(hd, wq.x, aq.x); aq.y = fmaf(hd, wq.y, aq.y);
        aq.z = fmaf(hd, wq.z, aq.z); aq.w = fmaf(hd, wq.w, aq.w);
        ak.x = fmaf(hd, wk.x, ak.x); ak.y = fmaf(hd, wk.y, ak.y);
        ak.z = fmaf(hd, wk.z, ak.z); ak.w = fmaf(hd, wk.w, ak.w);
        av.x = fmaf(hd, wv.x, av.x); av.y = fmaf(hd, wv.y, av.y);
        av.z = fmaf(hd, wv.z, av.z); av.w = fmaf(hd, wv.w, av.w);
    }
    const int n = n0 + t;
    ushort4 uq, uk;
    uq.x = f2b(aq.x); uq.y = f2b(aq.y); uq.z = f2b(aq.z); uq.w = f2b(aq.w);
    uk.x = f2b(ak.x); uk.y = f2b(ak.y); uk.z = f2b(ak.z); uk.w = f2b(ak.w);
    *(ushort4*)&q[n*64 + 4*j4] = uq;
    *(ushort4*)&k[n*64 + 4*j4] = uk;
    vt[(4*j4+0)*N_ + n] = f2b(av.x);
    vt[(4*j4+1)*N_ + n] = f2b(av.y);
    vt[(4*j4+2)*N_ + n] = f2b(av.z);
    vt[(4*j4+3)*N_ + n] = f2b(av.w);
}

// ---------------------------------------------------------------------------
// Flash attention, bf16 MFMA 16x16x32, no-max softmax (scores ~5e-5).
// Grid 800 = 200 q-tiles (TQ=32) x 4 KV-quarters (25 steps of 64).
// launch_bounds(256,4): LDS 36352B -> 4 blk/CU -> all 800 co-resident.
// NO atomics, NO cross-block fences (round-10 lesson: per-block device
// fences cost ~160us in L2 writeback storms): each KV-split plain-stores
// its own opart/lpart slice; k_vq sums slices deterministically.
// Fragment layouts validated on HW (rounds 4-9, absmax 4.9e-4).
// ---------------------------------------------------------------------------
__global__ __launch_bounds__(256, 4) void k_attn(
    const unsigned short* __restrict__ qg, const unsigned short* __restrict__ kg,
    const unsigned short* __restrict__ vtg,
    float* __restrict__ opart, float* __restrict__ lpart)
{
    __shared__ unsigned short Qs[32 * STRD];
    __shared__ unsigned short Ks[64 * STRD];
    __shared__ unsigned short Vts[64 * STRD];
    __shared__ unsigned short Ps[32 * STRD];
    __shared__ float Of[32 * 66];
    __shared__ float lred[2][32];

    const int tid  = threadIdx.x;
    const int qt   = blockIdx.x >> 2;
    const int sp   = blockIdx.x & 3;
    const int q0   = qt * 32;
    const int kvb  = sp * 1600;
    const int lane = tid & 63;
    const int w    = tid >> 6;
    const int m    = w & 1;          // q 16-row subtile
    const int s    = w >> 1;         // kv 32-col half of each step
    const int lr   = lane & 15;      // frag row/col id
    const int lg   = lane >> 4;      // frag k-group

    {   // stage Q tile: 32 rows x 64 bf16
        const int row = tid >> 3, ch = tid & 7;
        uint4 t = *(const uint4*)&qg[(q0 + row) * 64 + ch * 8];
        *(uint4*)&Qs[row * STRD + ch * 8] = t;
    }
    __syncthreads();
    const bf16x8_t qa0 = *(const bf16x8_t*)&Qs[(m*16 + lr) * STRD +  0 + lg*8];
    const bf16x8_t qa1 = *(const bf16x8_t*)&Qs[(m*16 + lr) * STRD + 32 + lg*8];

    f32x4_t o0 = {0.f,0.f,0.f,0.f}, o1 = {0.f,0.f,0.f,0.f};
    f32x4_t o2 = {0.f,0.f,0.f,0.f}, o3 = {0.f,0.f,0.f,0.f};
    float ls0 = 0.f, ls1 = 0.f, ls2 = 0.f, ls3 = 0.f;
    const float scale = 0.125f;   // 1/sqrt(64)

    for (int st = 0; st < 25; ++st) {
        __syncthreads();               // all waves done reading Ks/Vts
        const int j0 = kvb + st * 64;
        {   // stage K[64][64] and Vt[64][64]: 4 x 16B per thread
            const int row = tid >> 3, ch = tid & 7;     // row 0..31
            uint4 a = *(const uint4*)&kg [(j0 + row)      * 64 + ch*8];
            uint4 b = *(const uint4*)&kg [(j0 + row + 32) * 64 + ch*8];
            uint4 c = *(const uint4*)&vtg[ row       * N_ + j0 + ch*8];
            uint4 d = *(const uint4*)&vtg[(row + 32) * N_ + j0 + ch*8];
            *(uint4*)&Ks [ row      * STRD + ch*8] = a;
            *(uint4*)&Ks [(row+32)  * STRD + ch*8] = b;
            *(uint4*)&Vts[ row      * STRD + ch*8] = c;
            *(uint4*)&Vts[(row+32)  * STRD + ch*8] = d;
        }
        __syncthreads();

        // ---- QK^T + exp + P write (kv cols s*32 + t*16 + lr)
        #pragma unroll
        for (int t = 0; t < 2; ++t) {
            const int kcol = s*32 + t*16 + lr;
            bf16x8_t kb0 = *(const bf16x8_t*)&Ks[kcol * STRD +  0 + lg*8];
            bf16x8_t kb1 = *(const bf16x8_t*)&Ks[kcol * STRD + 32 + lg*8];
            f32x4_t acc = {0.f,0.f,0.f,0.f};
            acc = __builtin_amdgcn_mfma_f32_16x16x32_bf16(qa0, kb0, acc, 0, 0, 0);
            acc = __builtin_amdgcn_mfma_f32_16x16x32_bf16(qa1, kb1, acc, 0, 0, 0);
            const float p0 = __expf(acc[0] * scale);
            const float p1 = __expf(acc[1] * scale);
            const float p2 = __expf(acc[2] * scale);
            const float p3 = __expf(acc[3] * scale);
            ls0 += p0; ls1 += p1; ls2 += p2; ls3 += p3;
            const int rb = (m*16 + lg*4) * STRD + kcol;
            Ps[rb           ] = f2b(p0);
            Ps[rb +   STRD  ] = f2b(p1);
            Ps[rb + 2*STRD  ] = f2b(p2);
            Ps[rb + 3*STRD  ] = f2b(p3);
        }
        // no barrier: wave-private P region; in-wave lgkmcnt orders write->read

        // ---- PV over this wave's kv half
        const bf16x8_t pa = *(const bf16x8_t*)&Ps[(m*16 + lr) * STRD + s*32 + lg*8];
        {
            bf16x8_t vb;
            vb = *(const bf16x8_t*)&Vts[( 0 + lr) * STRD + s*32 + lg*8];
            o0 = __builtin_amdgcn_mfma_f32_16x16x32_bf16(pa, vb, o0, 0, 0, 0);
            vb = *(const bf16x8_t*)&Vts[(16 + lr) * STRD + s*32 + lg*8];
            o1 = __builtin_amdgcn_mfma_f32_16x16x32_bf16(pa, vb, o1, 0, 0, 0);
            vb = *(const bf16x8_t*)&Vts[(32 + lr) * STRD + s*32 + lg*8];
            o2 = __builtin_amdgcn_mfma_f32_16x16x32_bf16(pa, vb, o2, 0, 0, 0);
            vb = *(const bf16x8_t*)&Vts[(48 + lr) * STRD + s*32 + lg*8];
            o3 = __builtin_amdgcn_mfma_f32_16x16x32_bf16(pa, vb, o3, 0, 0, 0);
        }
    }

    // ---- row-sum reduce over the 16 kv-lanes, stash per (s, row)
    #pragma unroll
    for (int off = 1; off <= 8; off <<= 1) {
        ls0 += __shfl_xor(ls0, off);
        ls1 += __shfl_xor(ls1, off);
        ls2 += __shfl_xor(ls2, off);
        ls3 += __shfl_xor(ls3, off);
    }
    if (lr == 0) {
        const int rb = m*16 + lg*4;
        lred[s][rb    ] = ls0;
        lred[s][rb + 1] = ls1;
        lred[s][rb + 2] = ls2;
        lred[s][rb + 3] = ls3;
    }

    // ---- merge the two kv-half waves' O in LDS, plain-store to slice sp
    if (s == 0) {
        #pragma unroll
        for (int r = 0; r < 4; ++r) {
            const int row = m*16 + lg*4 + r;
            Of[row*66 +  0 + lr] = o0[r];
            Of[row*66 + 16 + lr] = o1[r];
            Of[row*66 + 32 + lr] = o2[r];
            Of[row*66 + 48 + lr] = o3[r];
        }
    }
    __syncthreads();
    if (s == 1) {
        float* op = opart + ((size_t)sp * N_ + q0) * 64;
        #pragma unroll
        for (int r = 0; r < 4; ++r) {
            const int row = m*16 + lg*4 + r;
            op[row*64 +  0 + lr] = Of[row*66 +  0 + lr] + o0[r];
            op[row*64 + 16 + lr] = Of[row*66 + 16 + lr] + o1[r];
            op[row*64 + 32 + lr] = Of[row*66 + 32 + lr] + o2[r];
            op[row*64 + 48 + lr] = Of[row*66 + 48 + lr] + o3[r];
        }
    }
    if (tid < 32) lpart[sp*N_ + q0 + tid] = lred[0][tid] + lred[1][tid];
}

// ---------------------------------------------------------------------------
// k_vq: deterministic 4-slice reduce -> f (bf16) -> MFMA argmin -> per-batch
// mean partials -> fused encoder matvec -> atomicAdd into out (init'd to benc).
// 400 blocks x 1 wave.  Strict < over ascending codes + (val,idx) shfl
// tie-break == jnp.argmin first-occurrence (HW-proven rounds 5-9).
// ---------------------------------------------------------------------------
__global__ __launch_bounds__(64) void k_vq(
    const float* __restrict__ opart, const float* __restrict__ lpart,
    const unsigned short* __restrict__ cbb, const float* __restrict__ cn,
    const float* __restrict__ cbf, const int* __restrict__ masks,
    const float* __restrict__ Wenc, float* __restrict__ out)
{
    const int lane = threadIdx.x;
    const int n0   = blockIdx.x * 16;
    const int lr   = lane & 15, lg = lane >> 4;
    const int row  = n0 + lr;

    const float l = lpart[row] + lpart[N_ + row] + lpart[2*N_ + row] + lpart[3*N_ + row];
    const float inv = 1.0f / l;      // lanes 0..15 hold inv for tokens 0..15

    // f fragments: deterministic sum of the 4 opart slices, then bf16 pack
    float fr[16];
    #pragma unroll
    for (int h = 0; h < 2; ++h) {     // h=0: dims lg*8.., h=1: dims 32+lg*8..
        const int base = row*64 + h*32 + lg*8;
        float4 s0 = *(const float4*)&opart[base];
        float4 s1 = *(const float4*)&opart[(size_t)N_*64   + base];
        float4 s2 = *(const float4*)&opart[(size_t)N_*64*2 + base];
        float4 s3 = *(const float4*)&opart[(size_t)N_*64*3 + base];
        float4 t0 = *(const float4*)&opart[base + 4];
        float4 t1 = *(const float4*)&opart[(size_t)N_*64   + base + 4];
        float4 t2 = *(const float4*)&opart[(size_t)N_*64*2 + base + 4];
        float4 t3 = *(const float4*)&opart[(size_t)N_*64*3 + base + 4];
        fr[h*8+0] = ((s0.x+s1.x)+s2.x)+s3.x;  fr[h*8+1] = ((s0.y+s1.y)+s2.y)+s3.y;
        fr[h*8+2] = ((s0.z+s1.z)+s2.z)+s3.z;  fr[h*8+3] = ((s0.w+s1.w)+s2.w)+s3.w;
        fr[h*8+4] = ((t0.x+t1.x)+t2.x)+t3.x;  fr[h*8+5] = ((t0.y+t1.y)+t2.y)+t3.y;
        fr[h*8+6] = ((t0.z+t1.z)+t2.z)+t3.z;  fr[h*8+7] = ((t0.w+t1.w)+t2.w)+t3.w;
    }
    bf16x8_t fa0, fa1;
    #pragma unroll
    for (int i = 0; i < 8; ++i) {
        fa0[i] = (short)f2b(fr[i]     * inv);
        fa1[i] = (short)f2b(fr[8 + i] * inv);
    }

    float best0 = 3.0e38f, best1 = 3.0e38f, best2 = 3.0e38f, best3 = 3.0e38f;
    int   bi0 = 0, bi1 = 0, bi2 = 0, bi3 = 0;

    #pragma unroll 4
    for (int st = 0; st < 64; ++st) {
        const int crow = st * 16 + lr;
        bf16x8_t cb0 = *(const bf16x8_t*)&cbb[crow * 64 +  0 + lg*8];
        bf16x8_t cb1 = *(const bf16x8_t*)&cbb[crow * 64 + 32 + lg*8];
        const float cnv = cn[crow];
        f32x4_t acc = {0.f,0.f,0.f,0.f};
        acc = __builtin_amdgcn_mfma_f32_16x16x32_bf16(fa0, cb0, acc, 0, 0, 0);
        acc = __builtin_amdgcn_mfma_f32_16x16x32_bf16(fa1, cb1, acc, 0, 0, 0);
        const float d0 = fmaf(-2.f, acc[0], cnv);
        const float d1 = fmaf(-2.f, acc[1], cnv);
        const float d2 = fmaf(-2.f, acc[2], cnv);
        const float d3 = fmaf(-2.f, acc[3], cnv);
        if (d0 < best0) { best0 = d0; bi0 = crow; }
        if (d1 < best1) { best1 = d1; bi1 = crow; }
        if (d2 < best2) { best2 = d2; bi2 = crow; }
        if (d3 < best3) { best3 = d3; bi3 = crow; }
    }

    #pragma unroll
    for (int off = 1; off <= 8; off <<= 1) {
        float ov; int oi;
        ov = __shfl_xor(best0, off); oi = __shfl_xor(bi0, off);
        if (ov < best0 || (ov == best0 && oi < bi0)) { best0 = ov; bi0 = oi; }
        ov = __shfl_xor(best1, off); oi = __shfl_xor(bi1, off);
        if (ov < best1 || (ov == best1 && oi < bi1)) { best1 = ov; bi1 = oi; }
        ov = __shfl_xor(best2, off); oi = __shfl_xor(bi2, off);
        if (ov < best2 || (ov == best2 && oi < bi2)) { best2 = ov; bi2 = oi; }
        ov = __shfl_xor(best3, off); oi = __shfl_xor(bi3, off);
        if (ov < best3 || (ov == best3 && oi < bi3)) { best3 = ov; bi3 = oi; }
    }
    // token t (= lg*4 + r) winner: register bi_{t&3} of lanes with lg == t>>2

    // ---- per-batch partial sums: lane = dim d
    const int d  = lane;
    const int b0 = n0 / 50;
    const int r0 = n0 - b0 * 50;
    float vq0 = 0.f, hi0 = 0.f, vq1 = 0.f, hi1 = 0.f;
    #pragma unroll
    for (int t = 0; t < 16; ++t) {
        int ci;
        switch (t & 3) {
            case 0:  ci = __shfl(bi0, (t >> 2) * 16); break;
            case 1:  ci = __shfl(bi1, (t >> 2) * 16); break;
            case 2:  ci = __shfl(bi2, (t >> 2) * 16); break;
            default: ci = __shfl(bi3, (t >> 2) * 16); break;
        }
        const float invt = __shfl(inv, t);
        const int   nb   = (n0 + t) * 64 + d;
        const float hv = (((opart[nb] + opart[(size_t)N_*64 + nb])
                         + opart[(size_t)N_*64*2 + nb]) + opart[(size_t)N_*64*3 + nb]) * invt;
        const float vv = cbf[ci * 64 + d];
        if (r0 + t < 50) { vq0 += vv; hi0 += hv; }
        else             { vq1 += vv; hi1 += hv; }
    }

    // ---- dn for b0 (and b0+1 if spanning), wave-reduced from masks
    int mv0 = (lane < 50) ? ((masks[b0*50 + lane] >= 1) ? 1 : 0) : 0;
    #pragma unroll
    for (int off = 1; off <= 32; off <<= 1) mv0 += __shfl_xor(mv0, off);
    const float dn0 = (float)mv0;

    // ---- fused encoder: contribution of this block to out[b][*]
    {
        const float iv = 1.0f / dn0, ih = 1.0f / (dn0 + 1e-9f);
        float c0 = 0.f;
        #pragma unroll 8
        for (int dp = 0; dp < 64; ++dp) {
            c0 = fmaf(__shfl(vq0, dp) * iv, Wenc[dp*64 + d], c0);
            c0 = fmaf(__shfl(hi0, dp) * ih, Wenc[(64 + dp)*64 + d], c0);
        }
        atomicAdd(&out[b0*64 + d], c0);
    }
    if (r0 + 15 >= 50) {
        const int b1 = b0 + 1;
        int mv1 = (lane < 50) ? ((masks[b1*50 + lane] >= 1) ? 1 : 0) : 0;
        #pragma unroll
        for (int off = 1; off <= 32; off <<= 1) mv1 += __shfl_xor(mv1, off);
        const float dn1 = (float)mv1;
        const float iv = 1.0f / dn1, ih = 1.0f / (dn1 + 1e-9f);
        float c1 = 0.f;
        #pragma unroll 8
        for (int dp = 0; dp < 64; ++dp) {
            c1 = fmaf(__shfl(vq1, dp) * iv, Wenc[dp*64 + d], c1);
            c1 = fmaf(__shfl(hi1, dp) * ih, Wenc[(64 + dp)*64 + d], c1);
        }
        atomicAdd(&out[b1*64 + d], c1);
    }
}

// ---------------------------------------------------------------------------
extern "C" void kernel_launch(void* const* d_in, const int* in_sizes, int n_in,
                              void* d_out, int out_size, void* d_ws, size_t ws_size,
                              hipStream_t stream)
{
    const int*   ids   = (const int*)  d_in[0];
    const int*   masks = (const int*)  d_in[1];
    const float* emb   = (const float*)d_in[2];
    const float* cb    = (const float*)d_in[3];
    const float* Wq    = (const float*)d_in[4];
    const float* bq    = (const float*)d_in[5];
    const float* Wk    = (const float*)d_in[6];
    const float* bk    = (const float*)d_in[7];
    const float* Wv    = (const float*)d_in[8];
    const float* bv    = (const float*)d_in[9];
    const float* Wenc  = (const float*)d_in[10];
    const float* benc  = (const float*)d_in[11];
    float* out = (float*)d_out;

    // workspace layout (bytes), total 9248768
    char* w = (char*)d_ws;
    unsigned short* qb    = (unsigned short*)(w);             //  819200
    unsigned short* kb    = (unsigned short*)(w +  819200);   //  819200
    unsigned short* vtb   = (unsigned short*)(w + 1638400);   //  819200
    float*          opart = (float*)        (w + 2457600);    // 6553600 (4 slices)
    float*          lpart = (float*)        (w + 9011200);    //  102400 (4 slices)
    float*          cn    = (float*)        (w + 9113600);    //    4096
    unsigned short* cbb   = (unsigned short*)(w + 9117696);   //  131072

    hipLaunchKernelGGL(k_qkv,  dim3(405), dim3(256), 0, stream,
                       ids, masks, emb, Wq, bq, Wk, bk, Wv, bv, cb, benc,
                       qb, kb, vtb, cn, cbb, out);
    hipLaunchKernelGGL(k_attn, dim3(800), dim3(256), 0, stream,
                       qb, kb, vtb, opart, lpart);
    hipLaunchKernelGGL(k_vq,   dim3(400), dim3(64),  0, stream,
                       opart, lpart, cbb, cn, cb, masks, Wenc, out);
}